// Round 1
// baseline (197.080 us; speedup 1.0000x reference)
//
#include <hip/hip_runtime.h>
#include <hip/hip_bf16.h>
#include <math.h>

// Problem constants
#define BATCH 256
#define DM    768
#define REPR  1024
#define FF    3072

// ---------------------------------------------------------------------------
// Tiled fp32 GEMM: C = act(A[M,K] @ W[K,N] + bias [+ resid])
// BM=32, BN=64, BK=32, 256 threads, 2x4 microtile per thread.
// ACT: 0 = bias only, 1 = bias + exact GELU, 2 = bias + residual add
// All of M,N,K are multiples of the tile dims for our three GEMMs -> no guards.
// ---------------------------------------------------------------------------
template<int ACT>
__global__ __launch_bounds__(256)
void gemm_f32(const float* __restrict__ A, const float* __restrict__ W,
              const float* __restrict__ bias, const float* __restrict__ resid,
              float* __restrict__ C, int M, int N, int K)
{
    __shared__ float As[32][36];   // +4 pad breaks bank aliasing on column reads
    __shared__ float Bs[32][64];

    const int tid = threadIdx.x;
    const int tx  = tid & 15;      // 16 cols of 4 -> 64
    const int ty  = tid >> 4;      // 16 rows of 2 -> 32
    const int row0 = blockIdx.y * 32;
    const int col0 = blockIdx.x * 64;

    const int ar = tid >> 3;          // 0..31
    const int ac = (tid & 7) * 4;     // 0..28
    const int br = tid & 15;          // 0..15 (rows br, br+16)
    const int bc = (tid >> 4) * 4;    // 0..60

    float acc[2][4] = {{0.f,0.f,0.f,0.f},{0.f,0.f,0.f,0.f}};

    for (int k0 = 0; k0 < K; k0 += 32) {
        // stage A tile [32][32]
        float4 av = *(const float4*)(&A[(size_t)(row0 + ar) * K + k0 + ac]);
        As[ar][ac + 0] = av.x;
        As[ar][ac + 1] = av.y;
        As[ar][ac + 2] = av.z;
        As[ar][ac + 3] = av.w;
        // stage B tile [32][64] (k-major rows)
        float4 b0 = *(const float4*)(&W[(size_t)(k0 + br)      * N + col0 + bc]);
        float4 b1 = *(const float4*)(&W[(size_t)(k0 + br + 16) * N + col0 + bc]);
        *(float4*)(&Bs[br][bc])      = b0;
        *(float4*)(&Bs[br + 16][bc]) = b1;
        __syncthreads();

        #pragma unroll
        for (int kk = 0; kk < 32; ++kk) {
            const float a0 = As[ty * 2 + 0][kk];
            const float a1 = As[ty * 2 + 1][kk];
            const float4 b = *(const float4*)(&Bs[kk][tx * 4]);
            acc[0][0] = fmaf(a0, b.x, acc[0][0]);
            acc[0][1] = fmaf(a0, b.y, acc[0][1]);
            acc[0][2] = fmaf(a0, b.z, acc[0][2]);
            acc[0][3] = fmaf(a0, b.w, acc[0][3]);
            acc[1][0] = fmaf(a1, b.x, acc[1][0]);
            acc[1][1] = fmaf(a1, b.y, acc[1][1]);
            acc[1][2] = fmaf(a1, b.z, acc[1][2]);
            acc[1][3] = fmaf(a1, b.w, acc[1][3]);
        }
        __syncthreads();
    }

    #pragma unroll
    for (int i = 0; i < 2; ++i) {
        const int r = row0 + ty * 2 + i;
        #pragma unroll
        for (int j = 0; j < 4; ++j) {
            const int c = col0 + tx * 4 + j;
            float v = acc[i][j] + bias[c];
            if (ACT == 1) {
                // exact GELU: 0.5*x*(1+erf(x/sqrt(2)))
                v = 0.5f * v * (1.0f + erff(v * 0.70710678118654752f));
            } else if (ACT == 2) {
                v += resid[(size_t)r * N + c];
            }
            C[(size_t)r * N + c] = v;
        }
    }
}

// ---------------------------------------------------------------------------
// Row LayerNorm over DM=768: one block (256 thr) per row, 3 elems/thread.
// ---------------------------------------------------------------------------
__global__ __launch_bounds__(256)
void ln_rows(const float* __restrict__ Y, const float* __restrict__ gamma,
             const float* __restrict__ beta, float* __restrict__ out)
{
    const int row  = blockIdx.x;
    const int tid  = threadIdx.x;
    const int lane = tid & 63;
    const int wave = tid >> 6;
    const float* y = Y + (size_t)row * DM;

    const float v0 = y[tid];
    const float v1 = y[tid + 256];
    const float v2 = y[tid + 512];

    __shared__ float red[4];

    float s = v0 + v1 + v2;
    #pragma unroll
    for (int off = 32; off > 0; off >>= 1) s += __shfl_down(s, off);
    if (lane == 0) red[wave] = s;
    __syncthreads();
    const float mu = (red[0] + red[1] + red[2] + red[3]) * (1.0f / 768.0f);
    __syncthreads();   // red reuse

    const float d0 = v0 - mu, d1 = v1 - mu, d2 = v2 - mu;
    float q = d0 * d0 + d1 * d1 + d2 * d2;
    #pragma unroll
    for (int off = 32; off > 0; off >>= 1) q += __shfl_down(q, off);
    if (lane == 0) red[wave] = q;
    __syncthreads();
    const float var = (red[0] + red[1] + red[2] + red[3]) * (1.0f / 768.0f);
    const float inv = rsqrtf(var + 1e-12f);

    float* o = out + (size_t)row * DM;
    o[tid]       = d0 * inv * gamma[tid]       + beta[tid];
    o[tid + 256] = d1 * inv * gamma[tid + 256] + beta[tid + 256];
    o[tid + 512] = d2 * inv * gamma[tid + 512] + beta[tid + 512];
}

// ---------------------------------------------------------------------------
// Launch: x = im_repr@Wv2+bv2 ; t = gelu(x@W1+b1) ; y = t@W2+b2+x ; LN(y)
// (self-attention + q2/k2 projections are provably dead: cross-attn K/V rows
//  are identical per batch -> softmax uniform -> ctx == V row == im_repr@Wv2+bv2)
// ---------------------------------------------------------------------------
extern "C" void kernel_launch(void* const* d_in, const int* in_sizes, int n_in,
                              void* d_out, int out_size, void* d_ws, size_t ws_size,
                              hipStream_t stream)
{
    const float* im_repr = (const float*)d_in[0];
    // d_in[1..11] unused (q_repr, self-attn weights, Wq2/bq2, Wk2/bk2)
    const float* Wv2  = (const float*)d_in[12];
    const float* bv2  = (const float*)d_in[13];
    const float* W1   = (const float*)d_in[14];
    const float* b1   = (const float*)d_in[15];
    const float* W2   = (const float*)d_in[16];
    const float* b2   = (const float*)d_in[17];
    const float* ln_g = (const float*)d_in[18];
    const float* ln_b = (const float*)d_in[19];
    float* out = (float*)d_out;

    float* x = (float*)d_ws;                       // [256, 768]
    float* t = x + (size_t)BATCH * DM;             // [256, 3072]
    float* y = t + (size_t)BATCH * FF;             // [256, 768]

    // GEMM1: x = im_repr @ Wv2 + bv2   (M=256, N=768, K=1024)
    gemm_f32<0><<<dim3(DM / 64, BATCH / 32), 256, 0, stream>>>(
        im_repr, Wv2, bv2, nullptr, x, BATCH, DM, REPR);

    // GEMM2: t = gelu(x @ W1 + b1)     (M=256, N=3072, K=768)
    gemm_f32<1><<<dim3(FF / 64, BATCH / 32), 256, 0, stream>>>(
        x, W1, b1, nullptr, t, BATCH, FF, DM);

    // GEMM3: y = t @ W2 + b2 + x       (M=256, N=768, K=3072)
    gemm_f32<2><<<dim3(DM / 64, BATCH / 32), 256, 0, stream>>>(
        t, W2, b2, x, y, BATCH, DM, FF);

    // LayerNorm rows -> out
    ln_rows<<<BATCH, 256, 0, stream>>>(y, ln_g, ln_b, out);
}

// Round 3
// 102.114 us; speedup vs baseline: 1.9300x; 1.9300x over previous
//
#include <hip/hip_runtime.h>
#include <hip/hip_bf16.h>
#include <math.h>

#define BATCH 256
#define DM    768
#define REPR  1024
#define FF    3072

typedef __attribute__((ext_vector_type(8))) short bf16x8;
typedef __attribute__((ext_vector_type(4))) float f32x4;

__device__ __forceinline__ unsigned bf16rne(float f){
  union{float f; unsigned u;} x; x.f = f;
  return (x.u + 0x7FFFu + ((x.u >> 16) & 1u)) >> 16;
}
__device__ __forceinline__ unsigned pk2(float lo, float hi){
  return bf16rne(lo) | (bf16rne(hi) << 16);
}

// ---------------------------------------------------------------------------
// C = act(A[M,K]@W[K,N] + bias), bf16 MFMA 16x16x32, BN=64, BK=32, 4 waves 2x2.
// B-tile staged to LDS TRANSPOSED: Bs[n][k] bf16, 64 cols x 32 k = 64B/col,
// chunk-XOR swizzled at 16B granularity: dword(n,k) = n*16 + ((k>>3)^((n>>2)&3))*4
// + ((k>>1)&3). Fragment read = one aligned ds_read_b128 (8 k-contiguous bf16,
// n = lane&15, k-octet = lane>>4 -- the standard m89-symmetric layout).
// A fragments loaded straight from global (A is L2-resident, <=3MB).
// ACT: 0 = +bias, 1 = +bias+exact gelu, 2 = raw partial (split-K slice)
// ---------------------------------------------------------------------------
template<int BM, int ACT>
__global__ __launch_bounds__(256)
void gemm_mfma(const float* __restrict__ A, const float* __restrict__ W,
               const float* __restrict__ bias, float* __restrict__ C,
               int N, int lda, int kcount)
{
  constexpr int MF = (BM == 64) ? 2 : 1;
  __shared__ unsigned Bs[2][1024];   // [buf][64 cols][16 dwords], swizzled

  // bijective XCD swizzle (nwg % 8 == 0 for all our grids)
  const int gx = gridDim.x, gy = gridDim.y;
  const int nwg = gx * gy;
  int id = blockIdx.y * gx + blockIdx.x;
  if ((nwg & 7) == 0) id = (id & 7) * (nwg >> 3) + (id >> 3);
  const int bx = id / gy, by = id % gy;

  const int tid  = threadIdx.x;
  const int lane = tid & 63, wid = tid >> 6;
  const int wr = wid >> 1, wc = wid & 1;
  const int row_base = by * BM + wr * (BM / 2);
  const int col_base = bx * 64 + wc * 32;
  const int kb  = blockIdx.z * kcount;
  const int Msz = gy * BM;

  // staging map: thread -> k-pair kp (rows 2kp,2kp+1), column quad g (cols 4g..4g+3)
  const int kp = tid >> 4, g = tid & 15;
  const float* wp0 = W + (size_t)(kb + 2 * kp) * N + bx * 64 + 4 * g;
  const int wbase = g * 64 + (((kp >> 2) ^ (g & 3)) << 2) + (kp & 3); // dword idx for col 4g

  // A fragment pointers: row = row_base + m*16 + (lane&15), k-octet = (lane>>4)*8
  const float* ap[2];
  #pragma unroll
  for (int m = 0; m < MF; ++m)
    ap[m] = A + (size_t)(row_base + m * 16 + (lane & 15)) * lda + kb + (lane >> 4) * 8;

  // B fragment read dword indices (16B-aligned)
  int rb[2];
  #pragma unroll
  for (int nf = 0; nf < 2; ++nf) {
    const int col = wc * 32 + nf * 16 + (lane & 15);
    const int q = lane >> 4;
    rb[nf] = col * 16 + ((q ^ ((col >> 2) & 3)) << 2);
  }

  f32x4 acc[MF][2];
  #pragma unroll
  for (int m = 0; m < MF; ++m) { acc[m][0] = (f32x4)(0.0f); acc[m][1] = (f32x4)(0.0f); }

  const int nsteps = kcount >> 5;

  // prologue: stage tile 0, prefetch A tile 0
  float4 cb0 = *(const float4*)wp0;
  float4 cb1 = *(const float4*)(wp0 + N);
  float4 ca0[2], ca1[2];
  #pragma unroll
  for (int m = 0; m < MF; ++m) {
    ca0[m] = *(const float4*)ap[m];
    ca1[m] = *(const float4*)(ap[m] + 4);
  }
  {
    const float* r0 = (const float*)&cb0; const float* r1 = (const float*)&cb1;
    #pragma unroll
    for (int j = 0; j < 4; ++j) Bs[0][wbase + j * 16] = pk2(r0[j], r1[j]);
  }
  __syncthreads();

  for (int t = 0; t < nsteps; ++t) {
    const int cur = t & 1;
    const bool more = (t + 1) < nsteps;
    float4 nb0, nb1, na0[2], na1[2];
    if (more) {  // issue next-tile global loads early; latency hides under MFMA
      const float* w2 = wp0 + (size_t)(t + 1) * 32 * N;
      nb0 = *(const float4*)w2;
      nb1 = *(const float4*)(w2 + N);
      #pragma unroll
      for (int m = 0; m < MF; ++m) {
        const float* a2 = ap[m] + (t + 1) * 32;
        na0[m] = *(const float4*)a2;
        na1[m] = *(const float4*)(a2 + 4);
      }
    }
    // B fragments: one b128 each from current buffer
    union { uint4 q; bf16x8 v; } bfr[2];
    #pragma unroll
    for (int nf = 0; nf < 2; ++nf)
      bfr[nf].q = *(const uint4*)(&Bs[cur][rb[nf]]);
    // pack current A tile to bf16
    union { unsigned u[4]; bf16x8 v; } afr[2];
    #pragma unroll
    for (int m = 0; m < MF; ++m) {
      afr[m].u[0] = pk2(ca0[m].x, ca0[m].y); afr[m].u[1] = pk2(ca0[m].z, ca0[m].w);
      afr[m].u[2] = pk2(ca1[m].x, ca1[m].y); afr[m].u[3] = pk2(ca1[m].z, ca1[m].w);
    }
    #pragma unroll
    for (int m = 0; m < MF; ++m)
      #pragma unroll
      for (int nf = 0; nf < 2; ++nf)
        acc[m][nf] = __builtin_amdgcn_mfma_f32_16x16x32_bf16(afr[m].v, bfr[nf].v, acc[m][nf], 0, 0, 0);
    if (more) {
      const float* r0 = (const float*)&nb0; const float* r1 = (const float*)&nb1;
      #pragma unroll
      for (int j = 0; j < 4; ++j) Bs[cur ^ 1][wbase + j * 16] = pk2(r0[j], r1[j]);
      #pragma unroll
      for (int m = 0; m < MF; ++m) { ca0[m] = na0[m]; ca1[m] = na1[m]; }
    }
    __syncthreads();  // one barrier/step: orders write(t+1 tile) vs read(t+1), and read(t) vs write(t+2)
  }

  // epilogue: D layout col=lane&15, row=(lane>>4)*4+reg (m89-verified)
  C += (size_t)blockIdx.z * Msz * N;
  #pragma unroll
  for (int m = 0; m < MF; ++m) {
    #pragma unroll
    for (int nf = 0; nf < 2; ++nf) {
      const int c = col_base + nf * 16 + (lane & 15);
      const float bv = (ACT == 2) ? 0.0f : bias[c];
      #pragma unroll
      for (int r = 0; r < 4; ++r) {
        const int row = row_base + m * 16 + (lane >> 4) * 4 + r;
        float v = acc[m][nf][r] + bv;
        if (ACT == 1) v = 0.5f * v * (1.0f + erff(v * 0.70710678118654752f));
        C[(size_t)row * N + c] = v;
      }
    }
  }
}

// out = LayerNorm(p[0] + p[1] + b2 + x), one block per row.
// xres/out intentionally NOT restrict: they alias (d_out); all reads precede
// the first __syncthreads, all writes follow the last one, blocks own rows.
__global__ __launch_bounds__(256)
void ln_fuse(const float* __restrict__ P, const float* __restrict__ b2,
             const float* xres, const float* __restrict__ g,
             const float* __restrict__ be, float* out)
{
  const int row = blockIdx.x, tid = threadIdx.x;
  const int lane = tid & 63, wave = tid >> 6;
  const float* p0 = P + (size_t)row * DM;
  const float* p1 = P + (size_t)BATCH * DM + (size_t)row * DM;
  const float* xr = xres + (size_t)row * DM;

  float v0 = p0[tid      ] + p1[tid      ] + b2[tid      ] + xr[tid      ];
  float v1 = p0[tid + 256] + p1[tid + 256] + b2[tid + 256] + xr[tid + 256];
  float v2 = p0[tid + 512] + p1[tid + 512] + b2[tid + 512] + xr[tid + 512];

  __shared__ float red[4];
  float s = v0 + v1 + v2;
  #pragma unroll
  for (int o = 32; o > 0; o >>= 1) s += __shfl_down(s, o);
  if (lane == 0) red[wave] = s;
  __syncthreads();
  const float mu = (red[0] + red[1] + red[2] + red[3]) * (1.0f / 768.0f);
  __syncthreads();
  const float d0 = v0 - mu, d1 = v1 - mu, d2 = v2 - mu;
  float q = d0*d0 + d1*d1 + d2*d2;
  #pragma unroll
  for (int o = 32; o > 0; o >>= 1) q += __shfl_down(q, o);
  if (lane == 0) red[wave] = q;
  __syncthreads();
  const float var = (red[0] + red[1] + red[2] + red[3]) * (1.0f / 768.0f);
  const float inv = rsqrtf(var + 1e-12f);

  float* o = out + (size_t)row * DM;
  o[tid      ] = d0 * inv * g[tid      ] + be[tid      ];
  o[tid + 256] = d1 * inv * g[tid + 256] + be[tid + 256];
  o[tid + 512] = d2 * inv * g[tid + 512] + be[tid + 512];
}

// x = im_repr@Wv2+bv2 (-> d_out as scratch); t = gelu(x@W1+b1);
// p[z] = t@W2 K-slices (split-K=2); out = LN(p0+p1+b2+x).
// ws = t (3MB) + p (1.5MB) = 4.5MB (proven available in round 1).
extern "C" void kernel_launch(void* const* d_in, const int* in_sizes, int n_in,
                              void* d_out, int out_size, void* d_ws, size_t ws_size,
                              hipStream_t stream)
{
  const float* im  = (const float*)d_in[0];
  const float* Wv2 = (const float*)d_in[12];
  const float* bv2 = (const float*)d_in[13];
  const float* W1  = (const float*)d_in[14];
  const float* b1  = (const float*)d_in[15];
  const float* W2  = (const float*)d_in[16];
  const float* b2  = (const float*)d_in[17];
  const float* g   = (const float*)d_in[18];
  const float* be  = (const float*)d_in[19];
  float* out = (float*)d_out;

  float* t = (float*)d_ws;                    // [256][3072]
  float* p = t + (size_t)BATCH * FF;          // [2][256][768]

  // G1: x = im_repr @ Wv2 + bv2   (M=256,N=768,K=1024) -> d_out
  gemm_mfma<32, 0><<<dim3(12, 8, 1), 256, 0, stream>>>(im, Wv2, bv2, out, DM, REPR, REPR);
  // G2: t = gelu(x @ W1 + b1)     (M=256,N=3072,K=768)
  gemm_mfma<64, 1><<<dim3(48, 4, 1), 256, 0, stream>>>(out, W1, b1, t, FF, DM, DM);
  // G3: p[z] = t @ W2 slice-z     (M=256,N=768,K=3072, split-K=2)
  gemm_mfma<32, 2><<<dim3(12, 8, 2), 256, 0, stream>>>(t, W2, nullptr, p, DM, FF, FF / 2);
  // LN(p0+p1+b2+x) -> out
  ln_fuse<<<BATCH, 256, 0, stream>>>(p, b2, out, g, be, out);
}

// Round 4
// 58.457 us; speedup vs baseline: 3.3714x; 1.7468x over previous
//
#include <hip/hip_runtime.h>
#include <hip/hip_bf16.h>
#include <math.h>

#define BATCH 256
#define DM    768
#define REPR  1024
#define FF    3072

typedef __attribute__((ext_vector_type(8))) short bf16x8;
typedef __attribute__((ext_vector_type(4))) float f32x4;

__device__ __forceinline__ unsigned bf16rne(float f){
  union{float f; unsigned u;} x; x.f = f;
  return (x.u + 0x7FFFu + ((x.u >> 16) & 1u)) >> 16;
}
__device__ __forceinline__ unsigned pk2(float lo, float hi){
  return bf16rne(lo) | (bf16rne(hi) << 16);
}

// ---------------------------------------------------------------------------
// prep: transpose+convert the three weight matrices W[K][N] f32 -> Wt[N][K]
// bf16 (64x64 LDS tiles), plus straight bf16 convert of im_repr.
// blocks: [0,192) Wv2, [192,768) W1, [768,1344) W2, [1344,1408) im.
// ---------------------------------------------------------------------------
__global__ __launch_bounds__(256)
void prep(const float* __restrict__ Wv2, const float* __restrict__ W1,
          const float* __restrict__ W2, const float* __restrict__ im,
          ushort* __restrict__ Wv2t, ushort* __restrict__ W1t,
          ushort* __restrict__ W2t, ushort* __restrict__ imbf)
{
  const int b = blockIdx.x, tid = threadIdx.x;
  if (b >= 1344) {                       // im convert: 64 blocks x 4096 elems
    const int base = (b - 1344) * 4096 + tid * 16;
    float4 v0 = *(const float4*)(im + base);
    float4 v1 = *(const float4*)(im + base + 4);
    float4 v2 = *(const float4*)(im + base + 8);
    float4 v3 = *(const float4*)(im + base + 12);
    uint4 o0 = { pk2(v0.x,v0.y), pk2(v0.z,v0.w), pk2(v1.x,v1.y), pk2(v1.z,v1.w) };
    uint4 o1 = { pk2(v2.x,v2.y), pk2(v2.z,v2.w), pk2(v3.x,v3.y), pk2(v3.z,v3.w) };
    *(uint4*)(imbf + base)     = o0;
    *(uint4*)(imbf + base + 8) = o1;
    return;
  }
  const float* src; ushort* dst; int K, N, rel;
  if (b < 192)      { src = Wv2; dst = Wv2t; K = REPR; N = DM; rel = b; }
  else if (b < 768) { src = W1;  dst = W1t;  K = DM;   N = FF; rel = b - 192; }
  else              { src = W2;  dst = W2t;  K = FF;   N = DM; rel = b - 768; }
  const int ntk = K >> 6;
  const int k0 = (rel % ntk) * 64, n0 = (rel / ntk) * 64;

  __shared__ float lds[64][65];          // +1 pad: phase-2 reads 2-way (free)
  #pragma unroll
  for (int p = 0; p < 4; ++p) {          // load 64k x 64n f32, coalesced
    const int r = p * 16 + (tid >> 4), c4 = (tid & 15) * 4;
    float4 v = *(const float4*)(src + (size_t)(k0 + r) * N + n0 + c4);
    lds[r][c4] = v.x; lds[r][c4+1] = v.y; lds[r][c4+2] = v.z; lds[r][c4+3] = v.w;
  }
  __syncthreads();
  #pragma unroll
  for (int p = 0; p < 4; ++p) {          // store transposed bf16, coalesced
    const int nn = p * 16 + (tid >> 4), k4 = (tid & 15) * 4;
    uint2 o = { pk2(lds[k4][nn], lds[k4+1][nn]),
                pk2(lds[k4+2][nn], lds[k4+3][nn]) };
    *(uint2*)(dst + (size_t)(n0 + nn) * K + k0 + k4) = o;
  }
}

// ---------------------------------------------------------------------------
// fixup_x: x = sum_z P1[z] + bv2 -> xf (f32, for LN residual) + xbf (bf16, A
// operand of G2). 192 blocks x 256 thr x 4 elems.
// ---------------------------------------------------------------------------
__global__ __launch_bounds__(256)
void fixup_x(const float* __restrict__ P1, const float* __restrict__ bv2,
             float* __restrict__ xf, ushort* __restrict__ xbf)
{
  const int e = (blockIdx.x * 256 + threadIdx.x) * 4;
  const int c = e % DM;
  float4 s = *(const float4*)(P1 + e);
  #pragma unroll
  for (int z = 1; z < 4; ++z) {
    float4 v = *(const float4*)(P1 + (size_t)z * BATCH * DM + e);
    s.x += v.x; s.y += v.y; s.z += v.z; s.w += v.w;
  }
  float4 bb = *(const float4*)(bv2 + c);
  s.x += bb.x; s.y += bb.y; s.z += bb.z; s.w += bb.w;
  *(float4*)(xf + e) = s;
  uint2 o = { pk2(s.x, s.y), pk2(s.z, s.w) };
  *(uint2*)(xbf + e) = o;
}

// ---------------------------------------------------------------------------
// gemm_rr: pure register GEMM, no LDS, no barriers. A bf16 [M][lda], Bt bf16
// [N][K] (pre-transposed). Block tile 32x64 (4 waves 2x2, wave 16x32). Depth-1
// register prefetch; waves independent -> TLP hides L2 latency.
// Frag mapping (verified round 3): input row/col = lane&15, k-octet = lane>>4;
// output col = lane&15, row = (lane>>4)*4 + r.
// EPI: 0 = raw f32 partial to outF[z][M][N]; 1 = +bias, exact gelu, bf16 outH.
// ---------------------------------------------------------------------------
template<int EPI>
__global__ __launch_bounds__(256)
void gemm_rr(const ushort* __restrict__ Abf, const ushort* __restrict__ Bt,
             const float* __restrict__ bias, float* __restrict__ outF,
             ushort* __restrict__ outH, int N, int K, int lda, int kcount)
{
  const int gx = gridDim.x, gy = gridDim.y;
  const int nwg = gx * gy;
  int id = blockIdx.y * gx + blockIdx.x;
  if ((nwg & 7) == 0) id = (id & 7) * (nwg >> 3) + (id >> 3);  // XCD swizzle
  const int bx = id / gy, by = id % gy;

  const int lane = threadIdx.x & 63, wid = threadIdx.x >> 6;
  const int wr = wid >> 1, wc = wid & 1;
  const int arow = by * 32 + wr * 16 + (lane & 15);
  const int colb = bx * 64 + wc * 32;
  const int kq = (lane >> 4) * 8;
  const int kb = blockIdx.z * kcount;

  const ushort* ap  = Abf + (size_t)arow * lda + kb + kq;
  const ushort* bp0 = Bt + (size_t)(colb + 0  + (lane & 15)) * K + kb + kq;
  const ushort* bp1 = Bt + (size_t)(colb + 16 + (lane & 15)) * K + kb + kq;

  f32x4 acc0 = (f32x4)(0.0f), acc1 = (f32x4)(0.0f);
  const int nsteps = kcount >> 5;

  union U { uint4 q; bf16x8 v; };
  U a_c, b0_c, b1_c;
  a_c.q  = *(const uint4*)ap;
  b0_c.q = *(const uint4*)bp0;
  b1_c.q = *(const uint4*)bp1;

  for (int t = 0; t < nsteps; ++t) {
    U a_n, b0_n, b1_n;
    const bool more = (t + 1) < nsteps;
    if (more) {                          // issue next-step loads before MFMA
      a_n.q  = *(const uint4*)(ap  + (t + 1) * 32);
      b0_n.q = *(const uint4*)(bp0 + (t + 1) * 32);
      b1_n.q = *(const uint4*)(bp1 + (t + 1) * 32);
    }
    acc0 = __builtin_amdgcn_mfma_f32_16x16x32_bf16(a_c.v, b0_c.v, acc0, 0, 0, 0);
    acc1 = __builtin_amdgcn_mfma_f32_16x16x32_bf16(a_c.v, b1_c.v, acc1, 0, 0, 0);
    if (more) { a_c = a_n; b0_c = b0_n; b1_c = b1_n; }
  }

  const int crow = by * 32 + wr * 16 + (lane >> 4) * 4;
  #pragma unroll
  for (int nf = 0; nf < 2; ++nf) {
    const int c = colb + nf * 16 + (lane & 15);
    const f32x4 a = nf ? acc1 : acc0;
    #pragma unroll
    for (int r = 0; r < 4; ++r) {
      const int row = crow + r;
      if (EPI == 0) {
        outF[(size_t)blockIdx.z * BATCH * N + (size_t)row * N + c] = a[r];
      } else {
        float v = a[r] + bias[c];
        v = 0.5f * v * (1.0f + erff(v * 0.70710678118654752f));
        outH[(size_t)row * N + c] = (ushort)bf16rne(v);
      }
    }
  }
}

// ---------------------------------------------------------------------------
// ln_final: y = xf + sum_z P3[z] + b2, then LayerNorm -> out. 1 block/row.
// ---------------------------------------------------------------------------
__global__ __launch_bounds__(256)
void ln_final(const float* __restrict__ P3, const float* __restrict__ xf,
              const float* __restrict__ b2, const float* __restrict__ g,
              const float* __restrict__ be, float* __restrict__ out)
{
  const int row = blockIdx.x, tid = threadIdx.x;
  const int lane = tid & 63, wave = tid >> 6;

  float v[3];
  #pragma unroll
  for (int i = 0; i < 3; ++i) {
    const int c = tid + i * 256;
    float s = xf[(size_t)row * DM + c] + b2[c];
    #pragma unroll
    for (int z = 0; z < 8; ++z) s += P3[((size_t)z * BATCH + row) * DM + c];
    v[i] = s;
  }

  __shared__ float red[4];
  float s = v[0] + v[1] + v[2];
  #pragma unroll
  for (int o = 32; o > 0; o >>= 1) s += __shfl_down(s, o);
  if (lane == 0) red[wave] = s;
  __syncthreads();
  const float mu = (red[0] + red[1] + red[2] + red[3]) * (1.0f / 768.0f);
  __syncthreads();
  const float d0 = v[0] - mu, d1 = v[1] - mu, d2 = v[2] - mu;
  float q = d0*d0 + d1*d1 + d2*d2;
  #pragma unroll
  for (int o = 32; o > 0; o >>= 1) q += __shfl_down(q, o);
  if (lane == 0) red[wave] = q;
  __syncthreads();
  const float var = (red[0] + red[1] + red[2] + red[3]) * (1.0f / 768.0f);
  const float inv = rsqrtf(var + 1e-12f);

  float* o = out + (size_t)row * DM;
  o[tid      ] = d0 * inv * g[tid      ] + be[tid      ];
  o[tid + 256] = d1 * inv * g[tid + 256] + be[tid + 256];
  o[tid + 512] = d2 * inv * g[tid + 512] + be[tid + 512];
}

// ---------------------------------------------------------------------------
// prep -> G1 (split-4) -> fixup_x -> G2 -> G3 (split-8) -> LN.
// ws usage ~23.7 MB (ws is ~346 MB per round-3 fill counters).
// ---------------------------------------------------------------------------
extern "C" void kernel_launch(void* const* d_in, const int* in_sizes, int n_in,
                              void* d_out, int out_size, void* d_ws, size_t ws_size,
                              hipStream_t stream)
{
  const float* im  = (const float*)d_in[0];
  const float* Wv2 = (const float*)d_in[12];
  const float* bv2 = (const float*)d_in[13];
  const float* W1  = (const float*)d_in[14];
  const float* b1  = (const float*)d_in[15];
  const float* W2  = (const float*)d_in[16];
  const float* b2  = (const float*)d_in[17];
  const float* g   = (const float*)d_in[18];
  const float* be  = (const float*)d_in[19];
  float* out = (float*)d_out;

  char* w = (char*)d_ws;
  ushort* Wv2t = (ushort*)(w);               // 768*1024*2  = 1572864
  ushort* W1t  = (ushort*)(w + 1572864);     // 3072*768*2  = 4718592
  ushort* W2t  = (ushort*)(w + 6291456);     // 768*3072*2  = 4718592
  ushort* imbf = (ushort*)(w + 11010048);    // 256*1024*2  = 524288
  ushort* xbf  = (ushort*)(w + 11534336);    // 256*768*2   = 393216
  ushort* tbf  = (ushort*)(w + 11927552);    // 256*3072*2  = 1572864
  float*  xf   = (float*) (w + 13500416);    // 256*768*4   = 786432
  float*  P1   = (float*) (w + 14286848);    // 4*256*768*4 = 3145728
  float*  P3   = (float*) (w + 17432576);    // 8*256*768*4 = 6291456 -> 23.7MB

  // T: transpose/convert weights + im
  prep<<<1408, 256, 0, stream>>>(Wv2, W1, W2, im, Wv2t, W1t, W2t, imbf);
  // G1: P1[z] = (im @ Wv2) K-slices   (M=256,N=768,K=1024, split-4)
  gemm_rr<0><<<dim3(12, 8, 4), 256, 0, stream>>>(imbf, Wv2t, nullptr, P1, nullptr,
                                                 DM, REPR, REPR, 256);
  // x = sum P1 + bv2 (f32 + bf16)
  fixup_x<<<192, 256, 0, stream>>>(P1, bv2, xf, xbf);
  // G2: tbf = bf16(gelu(x @ W1 + b1)) (M=256,N=3072,K=768)
  gemm_rr<1><<<dim3(48, 8, 1), 256, 0, stream>>>(xbf, W1t, b1, nullptr, tbf,
                                                 FF, DM, DM, DM);
  // G3: P3[z] = (t @ W2) K-slices     (M=256,N=768,K=3072, split-8)
  gemm_rr<0><<<dim3(12, 8, 8), 256, 0, stream>>>(tbf, W2t, nullptr, P3, nullptr,
                                                 DM, FF, FF, 384);
  // LN(x + sum P3 + b2) -> out
  ln_final<<<BATCH, 256, 0, stream>>>(P3, xf, b2, g, be, out);
}